// Round 4
// baseline (620.238 us; speedup 1.0000x reference)
//
#include <hip/hip_runtime.h>
#include <hip/hip_fp16.h>

// Problem constants
#define NV    884736     // 96^3 voxels
#define NB    3456       // NV / 256
#define DIM   96
#define DIM2  9216       // 96*96

// Fields stored as half4 (x,y,z,pad) = 8 B/voxel. A z-adjacent voxel PAIR is
// 16 contiguous bytes -> one dwordx4 gather covers both z-corners of a cell.

union H4 { uint2 u; __half2 h2[2]; };   // one voxel (8 B)
union H8 { uint4 u; __half2 h2[4]; };   // two z-adjacent voxels (16 B)

struct F3 { float x, y, z; };

__device__ __forceinline__ F3 lerp3(F3 a, F3 b, float t, float omt) {
    F3 r;
    r.x = a.x * omt + b.x * t;
    r.y = a.y * omt + b.y * t;
    r.z = a.z * omt + b.z * t;
    return r;
}

__device__ __forceinline__ uint2 pack_h4(float x, float y, float z) {
    H4 v;
    v.h2[0] = __floats2half2_rn(x, y);
    v.h2[1] = __floats2half2_rn(z, 0.0f);
    return v.u;
}

__device__ __forceinline__ F3 unpack_h4(uint2 raw) {
    H4 v; v.u = raw;
    float2 xy = __half22float2(v.h2[0]);
    float2 zp = __half22float2(v.h2[1]);
    F3 r; r.x = xy.x; r.y = xy.y; r.z = zp.x;
    return r;
}

// Border semantics EXACTLY as the reference:
//   x0 = clamp((int)floor(x),0,95); x1 = min(x0+1,95); fx = x - floor(x) (unclamped)
// z edge: when z0==95 force fz=0 so the second voxel of the 16B pair is
// multiplied by 0 (reference has c001==c000 there).
struct TriIdx { int x0, y0, z0, x1, y1; float fx, fy, fz; };

__device__ __forceinline__ TriIdx tri_prep(float x, float y, float z) {
    TriIdx t;
    float xf = floorf(x), yf = floorf(y), zf = floorf(z);
    t.fx = x - xf; t.fy = y - yf;
    float fz = z - zf;
    int x0 = (int)xf; x0 = x0 < 0 ? 0 : (x0 > DIM - 1 ? DIM - 1 : x0);
    int y0 = (int)yf; y0 = y0 < 0 ? 0 : (y0 > DIM - 1 ? DIM - 1 : y0);
    int z0 = (int)zf; z0 = z0 < 0 ? 0 : (z0 > DIM - 1 ? DIM - 1 : z0);
    int x1 = x0 + 1; if (x1 > DIM - 1) x1 = DIM - 1;
    int y1 = y0 + 1; if (y1 > DIM - 1) y1 = DIM - 1;
    t.x0 = x0; t.y0 = y0; t.z0 = z0; t.x1 = x1; t.y1 = y1;
    t.fz = (z0 < DIM - 1) ? fz : 0.0f;
    return t;
}

__device__ __forceinline__ void tri_gather_global(const uint2* __restrict__ f,
                                                  const TriIdx& t, H8 c[4]) {
    int i00 = t.x0 * DIM2 + t.y0 * DIM + t.z0;
    int i01 = t.x0 * DIM2 + t.y1 * DIM + t.z0;
    int i10 = t.x1 * DIM2 + t.y0 * DIM + t.z0;
    int i11 = t.x1 * DIM2 + t.y1 * DIM + t.z0;
    c[0].u = *(const uint4*)(f + i00);
    c[1].u = *(const uint4*)(f + i01);
    c[2].u = *(const uint4*)(f + i10);
    c[3].u = *(const uint4*)(f + i11);
}

__device__ __forceinline__ F3 tri_combine(const TriIdx& t, const H8 c[4]) {
    float gz = 1.0f - t.fz, gy = 1.0f - t.fy, gx = 1.0f - t.fx;
    F3 pz[4];
    #pragma unroll
    for (int q = 0; q < 4; q++) {
        float2 xy0 = __half22float2(c[q].h2[0]);
        float2 z0p = __half22float2(c[q].h2[1]);
        float2 xy1 = __half22float2(c[q].h2[2]);
        float2 z1p = __half22float2(c[q].h2[3]);
        F3 lo; lo.x = xy0.x; lo.y = xy0.y; lo.z = z0p.x;
        F3 hi; hi.x = xy1.x; hi.y = xy1.y; hi.z = z1p.x;
        pz[q] = lerp3(lo, hi, t.fz, gz);
    }
    F3 c0 = lerp3(pz[0], pz[1], t.fy, gy);
    F3 c1 = lerp3(pz[2], pz[3], t.fy, gy);
    return lerp3(c0, c1, t.fx, gx);
}

__device__ __forceinline__ int clampi(int v) {
    return v < 0 ? 0 : (v > DIM - 1 ? DIM - 1 : v);
}

// Init: v0 = +T/128 into fields 0..3, v0 = -T/128 into fields 4..7 (half4).
// Also zeroes the loss accumulator (d_out is poisoned before every timed launch).
__global__ __launch_bounds__(256) void init_kernel(const float* __restrict__ T,
                                                   uint2* __restrict__ bufA,
                                                   float* __restrict__ out) {
    int t = blockIdx.y;
    int l = blockIdx.x * 256 + threadIdx.x;
    if (t == 0 && l == 0) out[0] = 0.0f;
    const float inv = 1.0f / 128.0f;
    float vx = T[(size_t)(t * 3 + 0) * NV + l] * inv;
    float vy = T[(size_t)(t * 3 + 1) * NV + l] * inv;
    float vz = T[(size_t)(t * 3 + 2) * NV + l] * inv;
    bufA[(size_t)t * NV + l]       = pack_h4( vx,  vy,  vz);
    bufA[(size_t)(t + 4) * NV + l] = pack_h4(-vx, -vy, -vz);
}

// LDS-tiled scaling-and-squaring step. A block stages a TS^3 tile plus halo
// (HLO below / HHI above per axis, clamp-replicated at volume borders) into
// LDS, then every sample reads its 8 corners from LDS (ds_read, own pipe)
// instead of issuing divergent global gathers (TA-limited at ~1 addr/cyc/CU).
// Out-of-halo samples (shouldn't happen given the per-step displacement
// bound, but correctness must not depend on data) fall back to global gathers.
template<int TS, int HLO, int HHI>
__global__ __launch_bounds__(256) void step_tile_kernel(const uint2* __restrict__ src,
                                                        uint2* __restrict__ dst) {
    constexpr int L  = TS + HLO + HHI;   // staged extent per axis
    constexpr int L3 = L * L * L;
    constexpr int NT = DIM / TS;         // tiles per axis
    __shared__ uint2 tile[L3];

    int b = blockIdx.x;
    int f = b & 7;                        // field 0..7 (XCD-affine)
    int t = b >> 3;
    int tz = t % NT;
    int ty = (t / NT) % NT;
    int tx = t / (NT * NT);
    int gx0 = tx * TS, gy0 = ty * TS, gz0 = tz * TS;   // tile interior origin
    int ox = gx0 - HLO, oy = gy0 - HLO, oz = gz0 - HLO; // staged origin (unclamped)

    const uint2* __restrict__ s = src + (size_t)f * NV;
    uint2*       __restrict__ d = dst + (size_t)f * NV;

    // Stage tile+halo (clamp-replicated) into LDS; coalesced over z.
    for (int n = threadIdx.x; n < L3; n += 256) {
        int lz = n % L;
        int ly = (n / L) % L;
        int lx = n / (L * L);
        int gx = clampi(ox + lx), gy = clampi(oy + ly), gz = clampi(oz + lz);
        tile[n] = s[gx * DIM2 + gy * DIM + gz];
    }
    __syncthreads();

    // Compute TS^3 voxels, 256 threads, strided.
    for (int n = threadIdx.x; n < TS * TS * TS; n += 256) {
        int lz = n % TS;
        int ly = (n / TS) % TS;
        int lx = n / (TS * TS);
        int gi = gx0 + lx, gj = gy0 + ly, gk = gz0 + lz;

        F3 v = unpack_h4(tile[(lx + HLO) * (L * L) + (ly + HLO) * L + (lz + HLO)]);
        TriIdx tr = tri_prep((float)gi + v.x, (float)gj + v.y, (float)gk + v.z);

        int lx0 = tr.x0 - ox, lx1 = tr.x1 - ox;
        int ly0 = tr.y0 - oy, ly1 = tr.y1 - oy;
        int lz0 = tr.z0 - oz;
        bool inb = (lx0 >= 0) & (lx1 <= L - 1) &
                   (ly0 >= 0) & (ly1 <= L - 1) &
                   (lz0 >= 0) & (lz0 <= L - 2);

        H8 c[4];
        if (inb) {
            int b00 = lx0 * (L * L) + ly0 * L + lz0;
            int b01 = lx0 * (L * L) + ly1 * L + lz0;
            int b10 = lx1 * (L * L) + ly0 * L + lz0;
            int b11 = lx1 * (L * L) + ly1 * L + lz0;
            uint2 a0 = tile[b00], a1 = tile[b00 + 1];
            uint2 b0 = tile[b01], b1 = tile[b01 + 1];
            uint2 c0 = tile[b10], c1 = tile[b10 + 1];
            uint2 d0 = tile[b11], d1 = tile[b11 + 1];
            c[0].u = make_uint4(a0.x, a0.y, a1.x, a1.y);
            c[1].u = make_uint4(b0.x, b0.y, b1.x, b1.y);
            c[2].u = make_uint4(c0.x, c0.y, c1.x, c1.y);
            c[3].u = make_uint4(d0.x, d0.y, d1.x, d1.y);
        } else {
            tri_gather_global(s, tr, c);
        }
        F3 smp = tri_combine(tr, c);
        d[gi * DIM2 + gj * DIM + gk] = pack_h4(v.x + smp.x, v.y + smp.y, v.z + smp.z);
    }
}

// Compose + residual + loss for all 6 pairs, one thread per voxel.
__global__ __launch_bounds__(256) void loss_kernel(const uint2* __restrict__ fields,
                                                   const float* __restrict__ R,
                                                   float* __restrict__ out) {
    int l = blockIdx.x * 256 + threadIdx.x;
    int k = l % DIM;
    int j = (l / DIM) % DIM;
    int i = l / DIM2;
    float fi = (float)i, fj = (float)j, fk = (float)k;

    F3 f1c[3];
    #pragma unroll
    for (int r = 0; r < 3; r++)
        f1c[r] = unpack_h4(fields[(size_t)(4 + r) * NV + l]);

    float rbuf[18];
    const float* Rl = R + (size_t)l * 18;
    #pragma unroll
    for (int q = 0; q < 18; q++) rbuf[q] = Rl[q];

    const int REFI[6] = {0, 0, 0, 1, 1, 2};
    const int FLOI[6] = {1, 2, 3, 2, 3, 3};

    float acc = 0.0f;
    #pragma unroll
    for (int p = 0; p < 6; p += 2) {
        F3 f1a = f1c[REFI[p]];
        F3 f1b = f1c[REFI[p + 1]];
        const uint2* __restrict__ f2a = fields + (size_t)FLOI[p]     * NV;
        const uint2* __restrict__ f2b = fields + (size_t)FLOI[p + 1] * NV;
        TriIdx ta = tri_prep(fi + f1a.x, fj + f1a.y, fk + f1a.z);
        TriIdx tb = tri_prep(fi + f1b.x, fj + f1b.y, fk + f1b.z);
        H8 ca[4], cb[4];
        tri_gather_global(f2a, ta, ca);
        tri_gather_global(f2b, tb, cb);
        F3 sa = tri_combine(ta, ca);
        F3 sb = tri_combine(tb, cb);
        float rx = f1a.x + sa.x - rbuf[0 * 6 + p];
        float ry = f1a.y + sa.y - rbuf[1 * 6 + p];
        float rz = f1a.z + sa.z - rbuf[2 * 6 + p];
        acc += sqrtf(rx * rx + ry * ry + rz * rz);
        rx = f1b.x + sb.x - rbuf[0 * 6 + p + 1];
        ry = f1b.y + sb.y - rbuf[1 * 6 + p + 1];
        rz = f1b.z + sb.z - rbuf[2 * 6 + p + 1];
        acc += sqrtf(rx * rx + ry * ry + rz * rz);
    }

    __shared__ float wsum[4];
    int lane = threadIdx.x & 63;
    int wid  = threadIdx.x >> 6;
    #pragma unroll
    for (int off = 32; off > 0; off >>= 1)
        acc += __shfl_down(acc, off, 64);
    if (lane == 0) wsum[wid] = acc;
    __syncthreads();
    if (threadIdx.x == 0) {
        float s = wsum[0] + wsum[1] + wsum[2] + wsum[3];
        atomicAdd(out, s);
    }
}

extern "C" void kernel_launch(void* const* d_in, const int* in_sizes, int n_in,
                              void* d_out, int out_size, void* d_ws, size_t ws_size,
                              hipStream_t stream) {
    const float* T = (const float*)d_in[0];   // (4,3,96,96,96) fp32
    const float* R = (const float*)d_in[1];   // (96,96,96,3,6) fp32
    float* out = (float*)d_out;               // scalar loss

    // Two ping-pong buffers of 8 half4 fields (56.6 MB each) + 16B-gather slack.
    uint2* bufA = (uint2*)d_ws;
    uint2* bufB = bufA + (size_t)8 * NV + 32;

    dim3 blk(256);
    init_kernel<<<dim3(NB, 4), blk, 0, stream>>>(T, bufA, out);

    uint2* src = bufA;
    uint2* dst = bufB;
    // Displacement bound at step s is ~2^s/128 * max|v| (max|v|~5.2 for this
    // data): steps 0-4 <= 0.65 vox -> halo (1,2); step 5 <= 1.3 -> (2,3);
    // step 6 <= 2.6 -> (3,4). Fallback path covers any violation.
    for (int s = 0; s < 5; s++) {
        step_tile_kernel<16, 1, 2><<<6 * 6 * 6 * 8, blk, 0, stream>>>(src, dst);
        uint2* tmp = src; src = dst; dst = tmp;
    }
    step_tile_kernel<12, 2, 3><<<8 * 8 * 8 * 8, blk, 0, stream>>>(src, dst);
    { uint2* tmp = src; src = dst; dst = tmp; }
    step_tile_kernel<12, 3, 4><<<8 * 8 * 8 * 8, blk, 0, stream>>>(src, dst);
    { uint2* tmp = src; src = dst; dst = tmp; }

    loss_kernel<<<NB, blk, 0, stream>>>(src, R, out);
}

// Round 5
// 404.885 us; speedup vs baseline: 1.5319x; 1.5319x over previous
//
#include <hip/hip_runtime.h>
#include <hip/hip_fp16.h>

// Problem constants
#define NV    884736     // 96^3 voxels
#define NB    3456       // NV / 256
#define DIM   96
#define DIM2  9216       // 96*96

// Fields stored as half4 (x,y,z,pad) = 8 B/voxel. A z-adjacent voxel PAIR is
// 16 contiguous bytes -> one dwordx4 gather covers both z-corners of a cell.
// The gathered uint4 is directly 4x __half2 — the whole trilinear combine
// runs in packed-f16 (v_pk_fma_f16), no per-corner cvt to f32.

union H4 { uint2 u; __half2 h2[2]; };   // one voxel (8 B): (x,y),(z,0)
union H8 { uint4 u; __half2 h2[4]; };   // two z-adjacent voxels (16 B)

// packed-f16 lerp: lo + t*(hi-lo)   (2 instr: v_pk_add/sub + v_pk_fma)
__device__ __forceinline__ __half2 lerp_h2(__half2 lo, __half2 hi, __half2 t) {
    return __hfma2(t, __hsub2(hi, lo), lo);
}

// Border semantics EXACTLY as the reference:
//   x0 = clamp((int)floor(x),0,95); x1 = min(x0+1,95); fx = x - floor(x) (unclamped)
// z edge: when z0==95 force wz=0 so the second voxel of the 16B pair is
// multiplied by 0 (reference has c001==c000 there).
struct TriW { int i00, i01, i10, i11; __half2 wx, wy, wz; };

__device__ __forceinline__ TriW tri_prep(float x, float y, float z) {
    TriW t;
    float xf = floorf(x), yf = floorf(y), zf = floorf(z);
    float fx = x - xf, fy = y - yf, fz = z - zf;
    int x0 = (int)xf; x0 = x0 < 0 ? 0 : (x0 > DIM - 1 ? DIM - 1 : x0);
    int y0 = (int)yf; y0 = y0 < 0 ? 0 : (y0 > DIM - 1 ? DIM - 1 : y0);
    int z0 = (int)zf; z0 = z0 < 0 ? 0 : (z0 > DIM - 1 ? DIM - 1 : z0);
    int x1 = x0 + 1; if (x1 > DIM - 1) x1 = DIM - 1;
    int y1 = y0 + 1; if (y1 > DIM - 1) y1 = DIM - 1;
    t.wx = __float2half2_rn(fx);
    t.wy = __float2half2_rn(fy);
    t.wz = __float2half2_rn(z0 < DIM - 1 ? fz : 0.0f);
    int X0 = x0 * DIM2, X1 = x1 * DIM2;
    int Y0 = y0 * DIM,  Y1 = y1 * DIM;
    t.i00 = X0 + Y0 + z0;  t.i01 = X0 + Y1 + z0;
    t.i10 = X1 + Y0 + z0;  t.i11 = X1 + Y1 + z0;
    return t;
}

__device__ __forceinline__ void tri_gather(const uint2* __restrict__ f,
                                           const TriW& t, H8 c[4]) {
    c[0].u = *(const uint4*)(f + t.i00);
    c[1].u = *(const uint4*)(f + t.i01);
    c[2].u = *(const uint4*)(f + t.i10);
    c[3].u = *(const uint4*)(f + t.i11);
}

struct H2P { __half2 xy, z; };   // one sampled voxel value in packed f16

__device__ __forceinline__ H2P tri_combine(const TriW& t, const H8 c[4]) {
    // z-lerp inside each 16B pair: h2[0]/h2[1] = voxel z0, h2[2]/h2[3] = z0+1
    __half2 xy00 = lerp_h2(c[0].h2[0], c[0].h2[2], t.wz);
    __half2 z_00 = lerp_h2(c[0].h2[1], c[0].h2[3], t.wz);
    __half2 xy01 = lerp_h2(c[1].h2[0], c[1].h2[2], t.wz);
    __half2 z_01 = lerp_h2(c[1].h2[1], c[1].h2[3], t.wz);
    __half2 xy10 = lerp_h2(c[2].h2[0], c[2].h2[2], t.wz);
    __half2 z_10 = lerp_h2(c[2].h2[1], c[2].h2[3], t.wz);
    __half2 xy11 = lerp_h2(c[3].h2[0], c[3].h2[2], t.wz);
    __half2 z_11 = lerp_h2(c[3].h2[1], c[3].h2[3], t.wz);
    // y-lerp
    __half2 xy0 = lerp_h2(xy00, xy01, t.wy);
    __half2 z_0 = lerp_h2(z_00, z_01, t.wy);
    __half2 xy1 = lerp_h2(xy10, xy11, t.wy);
    __half2 z_1 = lerp_h2(z_10, z_11, t.wy);
    // x-lerp
    H2P r;
    r.xy = lerp_h2(xy0, xy1, t.wx);
    r.z  = lerp_h2(z_0, z_1, t.wx);
    return r;
}

// Init: v0 = +T/128 into fields 0..3, v0 = -T/128 into fields 4..7 (half4).
// Also zeroes the loss accumulator (d_out is poisoned before every timed launch).
__global__ __launch_bounds__(256) void init_kernel(const float* __restrict__ T,
                                                   uint2* __restrict__ bufA,
                                                   float* __restrict__ out) {
    int t = blockIdx.y;
    int l = blockIdx.x * 256 + threadIdx.x;
    if (t == 0 && l == 0) out[0] = 0.0f;
    const float inv = 1.0f / 128.0f;
    float vx = T[(size_t)(t * 3 + 0) * NV + l] * inv;
    float vy = T[(size_t)(t * 3 + 1) * NV + l] * inv;
    float vz = T[(size_t)(t * 3 + 2) * NV + l] * inv;
    H4 p; p.h2[0] = __floats2half2_rn( vx,  vy); p.h2[1] = __floats2half2_rn( vz, 0.0f);
    H4 n; n.h2[0] = __floats2half2_rn(-vx, -vy); n.h2[1] = __floats2half2_rn(-vz, 0.0f);
    bufA[(size_t)t * NV + l]       = p.u;
    bufA[(size_t)(t + 4) * NV + l] = n.u;
}

// One scaling-and-squaring step for all 8 fields: dst = src + sample(src, grid + src).
// field = blockIdx.x & 7 (XCD-affine under round-robin dispatch).
__global__ __launch_bounds__(256) void step_kernel(const uint2* __restrict__ src,
                                                   uint2* __restrict__ dst) {
    int g  = blockIdx.x;
    int f  = g & 7;
    int vb = g >> 3;
    const uint2* __restrict__ s = src + (size_t)f * NV;
    uint2*       __restrict__ d = dst + (size_t)f * NV;

    int l   = vb * 256 + threadIdx.x;
    int i   = l / DIM2;
    int rem = l % DIM2;
    int j   = rem / DIM;
    int k   = rem % DIM;

    H4 v; v.u = s[l];
    float2 vxy = __half22float2(v.h2[0]);
    float  vz  = __low2float(v.h2[1]);

    TriW t = tri_prep((float)i + vxy.x, (float)j + vxy.y, (float)k + vz);
    H8 c[4];
    tri_gather(s, t, c);
    H2P smp = tri_combine(t, c);

    H4 o;
    o.h2[0] = __hadd2(v.h2[0], smp.xy);   // (x,y)
    o.h2[1] = __hadd2(v.h2[1], smp.z);    // (z, 0+0)
    d[l] = o.u;
}

// Compose + residual + loss for all 6 pairs, one thread per voxel.
__global__ __launch_bounds__(256) void loss_kernel(const uint2* __restrict__ fields,
                                                   const float* __restrict__ R,
                                                   float* __restrict__ out) {
    int l = blockIdx.x * 256 + threadIdx.x;
    int k = l % DIM;
    int j = (l / DIM) % DIM;
    int i = l / DIM2;
    float fi = (float)i, fj = (float)j, fk = (float)k;

    // F_neg for ref indices 0,1,2 (fields 4,5,6)
    H4 f1c[3];
    #pragma unroll
    for (int r = 0; r < 3; r++)
        f1c[r].u = fields[(size_t)(4 + r) * NV + l];

    // R is (96,96,96,3,6): voxel-major, then channel, then pair. 18 floats/voxel.
    float rbuf[18];
    const float* Rl = R + (size_t)l * 18;
    #pragma unroll
    for (int q = 0; q < 18; q++) rbuf[q] = Rl[q];

    const int REFI[6] = {0, 0, 0, 1, 1, 2};
    const int FLOI[6] = {1, 2, 3, 2, 3, 3};

    float acc = 0.0f;
    #pragma unroll
    for (int p = 0; p < 6; p++) {
        H4 f1 = f1c[REFI[p]];
        float2 f1xy = __half22float2(f1.h2[0]);
        float  f1z  = __low2float(f1.h2[1]);
        const uint2* __restrict__ f2 = fields + (size_t)FLOI[p] * NV;
        TriW t = tri_prep(fi + f1xy.x, fj + f1xy.y, fk + f1z);
        H8 c[4];
        tri_gather(f2, t, c);
        H2P s = tri_combine(t, c);
        // R_hat = f1 + sample (packed f16), then residual in f32
        __half2 hxy = __hadd2(f1.h2[0], s.xy);
        __half2 hz  = __hadd2(f1.h2[1], s.z);
        float2 sxy = __half22float2(hxy);
        float  sz  = __low2float(hz);
        float rx = sxy.x - rbuf[0 * 6 + p];
        float ry = sxy.y - rbuf[1 * 6 + p];
        float rz = sz    - rbuf[2 * 6 + p];
        acc += sqrtf(rx * rx + ry * ry + rz * rz);
    }

    __shared__ float wsum[4];
    int lane = threadIdx.x & 63;
    int wid  = threadIdx.x >> 6;
    #pragma unroll
    for (int off = 32; off > 0; off >>= 1)
        acc += __shfl_down(acc, off, 64);
    if (lane == 0) wsum[wid] = acc;
    __syncthreads();
    if (threadIdx.x == 0) {
        float s = wsum[0] + wsum[1] + wsum[2] + wsum[3];
        atomicAdd(out, s);
    }
}

extern "C" void kernel_launch(void* const* d_in, const int* in_sizes, int n_in,
                              void* d_out, int out_size, void* d_ws, size_t ws_size,
                              hipStream_t stream) {
    const float* T = (const float*)d_in[0];   // (4,3,96,96,96) fp32
    const float* R = (const float*)d_in[1];   // (96,96,96,3,6) fp32
    float* out = (float*)d_out;               // scalar loss

    // Two ping-pong buffers of 8 half4 fields (56.6 MB each) + 16B-gather slack.
    uint2* bufA = (uint2*)d_ws;
    uint2* bufB = bufA + (size_t)8 * NV + 32;

    dim3 blk(256);
    init_kernel<<<dim3(NB, 4), blk, 0, stream>>>(T, bufA, out);

    uint2* src = bufA;
    uint2* dst = bufB;
    for (int s = 0; s < 7; s++) {
        step_kernel<<<NB * 8, blk, 0, stream>>>(src, dst);
        uint2* tmp = src; src = dst; dst = tmp;
    }
    // After 7 steps, final fields are in `src`.
    loss_kernel<<<NB, blk, 0, stream>>>(src, R, out);
}

// Round 7
// 401.816 us; speedup vs baseline: 1.5436x; 1.0076x over previous
//
#include <hip/hip_runtime.h>
#include <hip/hip_fp16.h>

// Problem constants
#define NV    884736     // 96^3 voxels
#define NB    3456       // NV / 256
#define DIM   96
#define DIM2  9216       // 96*96
#define TS    12         // tile size (DIM/TS = 8 tiles per axis)

// Fields stored as half4 (x,y,z,pad) = 8 B/voxel. A z-adjacent voxel PAIR is
// 16 contiguous bytes. Trilinear combine runs in packed f16 (v_pk_fma_f16).
//
// R6 lesson: NO raw asm loads (WAW on landing regs -> GPU fault).
// R1/R5 lesson: per-CU gather request throughput (~1.4 lane-req/cy/CU) is the
// limiter, not latency and not VALU. This round: LDS tiles dedup requests.

union H4 { uint2 u; __half2 h2[2]; };   // one voxel (8 B): (x,y),(z,0)
struct H8 { __half2 h2[4]; };           // two z-adjacent voxels

__device__ __forceinline__ __half2 lerp_h2(__half2 lo, __half2 hi, __half2 t) {
    return __hfma2(t, __hsub2(hi, lo), lo);
}

__device__ __forceinline__ int clampi(int v) {
    return v < 0 ? 0 : (v > DIM - 1 ? DIM - 1 : v);
}

// Border semantics EXACTLY as the reference:
//   x0 = clamp((int)floor(x),0,95); x1 = min(x0+1,95); fx = x - floor(x) (unclamped)
// z edge: when z0==95 force wz=0 so the second voxel of the z-pair is
// multiplied by 0 (reference has c001==c000 there).
struct TriP { int x0, y0, z0, x1, y1; __half2 wx, wy, wz; };

__device__ __forceinline__ TriP tri_prep(float x, float y, float z) {
    TriP t;
    float xf = floorf(x), yf = floorf(y), zf = floorf(z);
    float fx = x - xf, fy = y - yf, fz = z - zf;
    int x0 = (int)xf; x0 = x0 < 0 ? 0 : (x0 > DIM - 1 ? DIM - 1 : x0);
    int y0 = (int)yf; y0 = y0 < 0 ? 0 : (y0 > DIM - 1 ? DIM - 1 : y0);
    int z0 = (int)zf; z0 = z0 < 0 ? 0 : (z0 > DIM - 1 ? DIM - 1 : z0);
    int x1 = x0 + 1; if (x1 > DIM - 1) x1 = DIM - 1;
    int y1 = y0 + 1; if (y1 > DIM - 1) y1 = DIM - 1;
    t.x0 = x0; t.y0 = y0; t.z0 = z0; t.x1 = x1; t.y1 = y1;
    t.wx = __float2half2_rn(fx);
    t.wy = __float2half2_rn(fy);
    t.wz = __float2half2_rn(z0 < DIM - 1 ? fz : 0.0f);
    return t;
}

__device__ __forceinline__ void tri_gather_global(const uint2* __restrict__ f,
                                                  const TriP& t, H8 c[4]) {
    int i00 = t.x0 * DIM2 + t.y0 * DIM + t.z0;
    int i01 = t.x0 * DIM2 + t.y1 * DIM + t.z0;
    int i10 = t.x1 * DIM2 + t.y0 * DIM + t.z0;
    int i11 = t.x1 * DIM2 + t.y1 * DIM + t.z0;
    *(uint4*)&c[0] = *(const uint4*)(f + i00);
    *(uint4*)&c[1] = *(const uint4*)(f + i01);
    *(uint4*)&c[2] = *(const uint4*)(f + i10);
    *(uint4*)&c[3] = *(const uint4*)(f + i11);
}

struct H2P { __half2 xy, z; };

__device__ __forceinline__ H2P tri_combine(const TriP& t, const H8 c[4]) {
    __half2 xy00 = lerp_h2(c[0].h2[0], c[0].h2[2], t.wz);
    __half2 z_00 = lerp_h2(c[0].h2[1], c[0].h2[3], t.wz);
    __half2 xy01 = lerp_h2(c[1].h2[0], c[1].h2[2], t.wz);
    __half2 z_01 = lerp_h2(c[1].h2[1], c[1].h2[3], t.wz);
    __half2 xy10 = lerp_h2(c[2].h2[0], c[2].h2[2], t.wz);
    __half2 z_10 = lerp_h2(c[2].h2[1], c[2].h2[3], t.wz);
    __half2 xy11 = lerp_h2(c[3].h2[0], c[3].h2[2], t.wz);
    __half2 z_11 = lerp_h2(c[3].h2[1], c[3].h2[3], t.wz);
    __half2 xy0 = lerp_h2(xy00, xy01, t.wy);
    __half2 z_0 = lerp_h2(z_00, z_01, t.wy);
    __half2 xy1 = lerp_h2(xy10, xy11, t.wy);
    __half2 z_1 = lerp_h2(z_10, z_11, t.wy);
    H2P r;
    r.xy = lerp_h2(xy0, xy1, t.wx);
    r.z  = lerp_h2(z_0, z_1, t.wx);
    return r;
}

// Init: v0 = +T/128 into fields 0..3, v0 = -T/128 into fields 4..7 (half4).
// Also zeroes the loss accumulator (d_out is poisoned before every timed launch).
__global__ __launch_bounds__(256) void init_kernel(const float* __restrict__ T,
                                                   uint2* __restrict__ bufA,
                                                   float* __restrict__ out) {
    int t = blockIdx.y;
    int l = blockIdx.x * 256 + threadIdx.x;
    if (t == 0 && l == 0) out[0] = 0.0f;
    const float inv = 1.0f / 128.0f;
    float vx = T[(size_t)(t * 3 + 0) * NV + l] * inv;
    float vy = T[(size_t)(t * 3 + 1) * NV + l] * inv;
    float vz = T[(size_t)(t * 3 + 2) * NV + l] * inv;
    H4 p; p.h2[0] = __floats2half2_rn( vx,  vy); p.h2[1] = __floats2half2_rn( vz, 0.0f);
    H4 n; n.h2[0] = __floats2half2_rn(-vx, -vy); n.h2[1] = __floats2half2_rn(-vz, 0.0f);
    bufA[(size_t)t * NV + l]       = p.u;
    bufA[(size_t)(t + 4) * NV + l] = n.u;
}

// LDS-tiled scaling-and-squaring step. 12^3 tile, per-axis halo (HLO, HHI)
// (z gets +1 high halo for the z-pair read). Staging is row-cooperative
// (LPR lanes per (x,y) row, coalesced over z, no inner div/mod). Samples read
// 8 corners from LDS; out-of-halo samples (never expected; correctness must
// be data-independent) fall back to global gathers.
template<int HLO, int HHI>
__global__ __launch_bounds__(256) void step_tile_kernel(const uint2* __restrict__ src,
                                                        uint2* __restrict__ dst) {
    constexpr int Lxy = TS + HLO + HHI;
    constexpr int Lz  = Lxy + 1;                 // +1 high-z for pair reads
    constexpr int R   = Lxy * Lxy;               // rows to stage
    constexpr int SZ  = R * Lz;
    constexpr int LPR = (Lz <= 16) ? 16 : 32;    // lanes per row (pow2)
    constexpr int RPI = 256 / LPR;               // rows per iteration
    constexpr int NIT = (R + RPI - 1) / RPI;
    __shared__ uint2 tile[SZ];

    int b = blockIdx.x;
    int f = b & 7;                               // field (XCD-affine)
    int t = b >> 3;
    int tz = t & 7, ty = (t >> 3) & 7, tx = t >> 6;
    int gx0 = tx * TS, gy0 = ty * TS, gz0 = tz * TS;
    int ox = gx0 - HLO, oy = gy0 - HLO, oz = gz0 - HLO;

    const uint2* __restrict__ s = src + (size_t)f * NV;
    uint2*       __restrict__ d = dst + (size_t)f * NV;

    // ---- stage tile+halo (clamp-replicated), row-cooperative ----
    int rr = threadIdx.x / LPR;
    int wz = threadIdx.x % LPR;
    int gz = clampi(oz + wz);
    #pragma unroll
    for (int it = 0; it < NIT; it++) {
        int r = it * RPI + rr;
        if (r < R && wz < Lz) {
            int lx = r / Lxy;
            int ly = r - lx * Lxy;
            int gx = clampi(ox + lx);
            int gy = clampi(oy + ly);
            tile[r * Lz + wz] = s[gx * DIM2 + gy * DIM + gz];
        }
    }
    __syncthreads();

    // ---- compute TS^3 voxels ----
    #pragma unroll
    for (int it = 0; it < (TS * TS * TS + 255) / 256; it++) {
        int n = it * 256 + threadIdx.x;
        if (n >= TS * TS * TS) break;
        int lz = n % TS;
        int t1 = n / TS;
        int ly = t1 % TS;
        int lx = t1 / TS;
        int gi = gx0 + lx, gj = gy0 + ly, gk = gz0 + lz;

        H4 v;
        v.u = tile[((lx + HLO) * Lxy + (ly + HLO)) * Lz + (lz + HLO)];
        float2 vxy = __half22float2(v.h2[0]);
        float  vz  = __low2float(v.h2[1]);
        TriP p = tri_prep((float)gi + vxy.x, (float)gj + vxy.y, (float)gk + vz);

        int lx0 = p.x0 - ox, lx1 = p.x1 - ox;
        int ly0 = p.y0 - oy, ly1 = p.y1 - oy;
        int lz0 = p.z0 - oz;
        bool inb = (lx0 >= 0) & (lx1 <= Lxy - 1) &
                   (ly0 >= 0) & (ly1 <= Lxy - 1) &
                   (lz0 >= 0) & (lz0 <= Lz - 2);

        H8 c[4];
        if (inb) {
            int b00 = (lx0 * Lxy + ly0) * Lz + lz0;
            int b01 = (lx0 * Lxy + ly1) * Lz + lz0;
            int b10 = (lx1 * Lxy + ly0) * Lz + lz0;
            int b11 = (lx1 * Lxy + ly1) * Lz + lz0;
            uint2 a0 = tile[b00], a1 = tile[b00 + 1];
            uint2 b0 = tile[b01], b1 = tile[b01 + 1];
            uint2 c0 = tile[b10], c1 = tile[b10 + 1];
            uint2 d0 = tile[b11], d1 = tile[b11 + 1];
            *(uint4*)&c[0] = make_uint4(a0.x, a0.y, a1.x, a1.y);
            *(uint4*)&c[1] = make_uint4(b0.x, b0.y, b1.x, b1.y);
            *(uint4*)&c[2] = make_uint4(c0.x, c0.y, c1.x, c1.y);
            *(uint4*)&c[3] = make_uint4(d0.x, d0.y, d1.x, d1.y);
        } else {
            tri_gather_global(s, p, c);
        }
        H2P smp = tri_combine(p, c);
        H4 o;
        o.h2[0] = __hadd2(v.h2[0], smp.xy);
        o.h2[1] = __hadd2(v.h2[1], smp.z);
        d[gi * DIM2 + gj * DIM + gk] = o.u;
    }
}

// Compose + residual + loss for all 6 pairs, one thread per voxel (plain loads).
__global__ __launch_bounds__(256) void loss_kernel(const uint2* __restrict__ fields,
                                                   const float* __restrict__ R,
                                                   float* __restrict__ out) {
    int l = blockIdx.x * 256 + threadIdx.x;
    int k = l % DIM;
    int j = (l / DIM) % DIM;
    int i = l / DIM2;
    float fi = (float)i, fj = (float)j, fk = (float)k;

    H4 f1c[3];
    #pragma unroll
    for (int r = 0; r < 3; r++)
        f1c[r].u = fields[(size_t)(4 + r) * NV + l];

    float rbuf[18];
    const float* Rl = R + (size_t)l * 18;
    #pragma unroll
    for (int q = 0; q < 18; q++) rbuf[q] = Rl[q];

    const int REFI[6] = {0, 0, 0, 1, 1, 2};
    const int FLOI[6] = {1, 2, 3, 2, 3, 3};

    float acc = 0.0f;
    #pragma unroll
    for (int p = 0; p < 6; p++) {
        H4 f1 = f1c[REFI[p]];
        float2 f1xy = __half22float2(f1.h2[0]);
        float  f1z  = __low2float(f1.h2[1]);
        const uint2* __restrict__ f2 = fields + (size_t)FLOI[p] * NV;
        TriP t = tri_prep(fi + f1xy.x, fj + f1xy.y, fk + f1z);
        H8 c[4];
        tri_gather_global(f2, t, c);
        H2P s = tri_combine(t, c);
        __half2 hxy = __hadd2(f1.h2[0], s.xy);
        __half2 hz  = __hadd2(f1.h2[1], s.z);
        float2 sxy = __half22float2(hxy);
        float  sz  = __low2float(hz);
        float rx = sxy.x - rbuf[0 * 6 + p];
        float ry = sxy.y - rbuf[1 * 6 + p];
        float rz = sz    - rbuf[2 * 6 + p];
        acc += sqrtf(rx * rx + ry * ry + rz * rz);
    }

    __shared__ float wsum[4];
    int lane = threadIdx.x & 63;
    int wid  = threadIdx.x >> 6;
    #pragma unroll
    for (int off = 32; off > 0; off >>= 1)
        acc += __shfl_down(acc, off, 64);
    if (lane == 0) wsum[wid] = acc;
    __syncthreads();
    if (threadIdx.x == 0) {
        float s = wsum[0] + wsum[1] + wsum[2] + wsum[3];
        atomicAdd(out, s);
    }
}

extern "C" void kernel_launch(void* const* d_in, const int* in_sizes, int n_in,
                              void* d_out, int out_size, void* d_ws, size_t ws_size,
                              hipStream_t stream) {
    const float* T = (const float*)d_in[0];   // (4,3,96,96,96) fp32
    const float* R = (const float*)d_in[1];   // (96,96,96,3,6) fp32
    float* out = (float*)d_out;               // scalar loss

    // Two ping-pong buffers of 8 half4 fields (56.6 MB each) + 16B-gather slack.
    uint2* bufA = (uint2*)d_ws;
    uint2* bufB = bufA + (size_t)8 * NV + 32;

    dim3 blk(256);
    init_kernel<<<dim3(NB, 4), blk, 0, stream>>>(T, bufA, out);

    uint2* src = bufA;
    uint2* dst = bufB;
    const int grid_tiles = 8 * 8 * 8 * 8;   // 512 tiles x 8 fields
    // Displacement bound at input of step s ~= 2^s/128 * max|v| (max|v|~5.2):
    // steps 0-4 <= 0.65 -> halo (1,1); step 5 <= 1.3 -> (2,2); step 6 <= 2.6
    // -> (3,3). Fallback path covers any violation.
    for (int s = 0; s < 5; s++) {
        step_tile_kernel<1, 1><<<grid_tiles, blk, 0, stream>>>(src, dst);
        uint2* tmp = src; src = dst; dst = tmp;
    }
    step_tile_kernel<2, 2><<<grid_tiles, blk, 0, stream>>>(src, dst);
    { uint2* tmp = src; src = dst; dst = tmp; }
    step_tile_kernel<3, 3><<<grid_tiles, blk, 0, stream>>>(src, dst);
    { uint2* tmp = src; src = dst; dst = tmp; }

    loss_kernel<<<NB, blk, 0, stream>>>(src, R, out);
}